// Round 4
// baseline (1011.900 us; speedup 1.0000x reference)
//
#include <hip/hip_runtime.h>
#include <hip/hip_bf16.h>
#include <stdint.h>

#pragma clang fp contract(off)

#define FH 512
#define FW 512
#define NA 9
#define HW (FH*FW)
#define TOTAL (HW*NA)
#define PRE_NMS 12000
#define POST_NMS 2000
#define NMS_WORDS 188            // ceil(12000/64)
#define MROW 192                 // padded words per mask row (1536 B, 16B-aligned)
#define CAND_MAX 16384
#define NMS_TH 0.7f
#define MIN_SIZE_C 16.0f

// generate_anchors(16, (0.5,1,2), (8,16,32)) — classic py-faster-rcnn table
__constant__ float ANCH[NA][4] = {
  {-84.f,-40.f,99.f,55.f},
  {-176.f,-88.f,191.f,103.f},
  {-360.f,-184.f,375.f,199.f},
  {-56.f,-56.f,71.f,71.f},
  {-120.f,-120.f,135.f,135.f},
  {-248.f,-248.f,263.f,263.f},
  {-36.f,-80.f,51.f,95.f},
  {-80.f,-168.f,95.f,183.f},
  {-168.f,-344.f,183.f,359.f}
};

__device__ __forceinline__ void decode_box(int a, int h, int w,
    const float* __restrict__ deltas, float im_h, float im_w,
    float& x1, float& y1, float& x2, float& y2) {
  float sx = (float)(w * 16);
  float sy = (float)(h * 16);
  float ax1 = ANCH[a][0] + sx;
  float ay1 = ANCH[a][1] + sy;
  float ax2 = ANCH[a][2] + sx;
  float ay2 = ANCH[a][3] + sy;
  float aw = ax2 - ax1 + 1.0f;
  float ah = ay2 - ay1 + 1.0f;
  float acx = ax1 + 0.5f * aw;
  float acy = ay1 + 0.5f * ah;
  int base = h * FW + w;
  float d0 = deltas[(4*a+0)*HW + base];
  float d1 = deltas[(4*a+1)*HW + base];
  float d2 = deltas[(4*a+2)*HW + base];
  float d3 = deltas[(4*a+3)*HW + base];
  float pcx = d0 * aw + acx;
  float pcy = d1 * ah + acy;
  float pw = expf(d2) * aw;
  float ph = expf(d3) * ah;
  x1 = pcx - 0.5f * pw;
  y1 = pcy - 0.5f * ph;
  x2 = pcx + 0.5f * pw;
  y2 = pcy + 0.5f * ph;
  x1 = fminf(fmaxf(x1, 0.0f), im_w - 1.0f);
  x2 = fminf(fmaxf(x2, 0.0f), im_w - 1.0f);
  y1 = fminf(fmaxf(y1, 0.0f), im_h - 1.0f);
  y2 = fminf(fmaxf(y2, 0.0f), im_h - 1.0f);
}

// keys + 8-bit (top byte) LDS-aggregated histogram.
__global__ void k_keys(const float* __restrict__ scores, const float* __restrict__ deltas,
                       const float* __restrict__ im_info, unsigned* __restrict__ keys,
                       unsigned* __restrict__ hist8) {
  __shared__ unsigned lh[256];
  int t = threadIdx.x;
  lh[t] = 0;
  __syncthreads();
  int base = blockIdx.x * blockDim.x + t;     // < HW by construction
  float im_h = im_info[0], im_w = im_info[1];
  float ms = MIN_SIZE_C * im_info[2];
  int h = base / FW, w = base % FW;
  for (int a = 0; a < NA; a++) {
    float x1, y1, x2, y2;
    decode_box(a, h, w, deltas, im_h, im_w, x1, y1, x2, y2);
    bool valid = ((x2 - x1 + 1.0f) >= ms) && ((y2 - y1 + 1.0f) >= ms);
    float sc = scores[(NA + a)*HW + base];
    float v = valid ? sc : -INFINITY;
    unsigned u = __float_as_uint(v);
    unsigned mono = (u & 0x80000000u) ? ~u : (u | 0x80000000u);
    keys[base*NA + a] = mono;
    atomicAdd(&lh[mono >> 24], 1u);
  }
  __syncthreads();
  atomicAdd(&hist8[t], lh[t]);
}

// per-block find8 (suffix scan of hist8) -> B8; histogram bits[23:9] of keys whose
// top byte == B8 into global hist15 (only ~50K elements -> cheap global atomics).
__global__ void __launch_bounds__(256) k_refine15(const unsigned* __restrict__ keys,
    const unsigned* __restrict__ hist8, unsigned* __restrict__ hist15) {
  __shared__ unsigned ssum[256];
  __shared__ unsigned sB8;
  int t = threadIdx.x;
  unsigned hv = hist8[t];
  ssum[t] = hv;
  __syncthreads();
  for (int off = 1; off < 256; off <<= 1) {
    unsigned v = ssum[t];
    unsigned add = (t + off < 256) ? ssum[t + off] : 0u;
    __syncthreads();
    ssum[t] = v + add;
    __syncthreads();
  }
  unsigned above = ssum[t] - hv;
  if (above < PRE_NMS && above + hv >= PRE_NMS) sB8 = (unsigned)t;
  __syncthreads();
  unsigned B8 = sB8;
  int stride = gridDim.x * blockDim.x;
  for (int i = blockIdx.x * blockDim.x + t; i < TOTAL; i += stride) {
    unsigned k = keys[i];
    if ((k >> 24) == B8) atomicAdd(&hist15[(k >> 9) & 0x7FFFu], 1u);
  }
}

// per-block find8 + find15 -> exact-bin threshold K; select keys >= K (<= ~12010 cands).
__global__ void __launch_bounds__(256) k_compact(const unsigned* __restrict__ keys,
    const unsigned* __restrict__ hist8, const unsigned* __restrict__ hist15,
    unsigned* __restrict__ cnt, unsigned long long* __restrict__ cand) {
  __shared__ unsigned ssum[256];
  __shared__ unsigned sB8, sT2, sB15;
  int t = threadIdx.x;
  // find8
  unsigned hv = hist8[t];
  ssum[t] = hv;
  __syncthreads();
  for (int off = 1; off < 256; off <<= 1) {
    unsigned v = ssum[t];
    unsigned add = (t + off < 256) ? ssum[t + off] : 0u;
    __syncthreads();
    ssum[t] = v + add;
    __syncthreads();
  }
  unsigned above = ssum[t] - hv;
  if (above < PRE_NMS && above + hv >= PRE_NMS) { sB8 = (unsigned)t; sT2 = PRE_NMS - above; }
  __syncthreads();
  unsigned B8 = sB8, T2 = sT2;
  // find15: thread t covers bins [t*128, t*128+128)
  unsigned loc = 0;
  for (int i = 0; i < 128; i++) loc += hist15[t*128 + i];
  __syncthreads();
  ssum[t] = loc;
  __syncthreads();
  for (int off = 1; off < 256; off <<= 1) {
    unsigned v = ssum[t];
    unsigned add = (t + off < 256) ? ssum[t + off] : 0u;
    __syncthreads();
    ssum[t] = v + add;
    __syncthreads();
  }
  unsigned above15 = ssum[t] - loc;         // count in bins above thread t's range
  unsigned acc = above15;
  for (int i = 127; i >= 0; i--) {
    unsigned cb = hist15[t*128 + i];
    acc += cb;
    if (acc >= T2 && acc - cb < T2) sB15 = (unsigned)(t*128 + i);
  }
  __syncthreads();
  unsigned K = (B8 << 24) | (sB15 << 9);
  int stride = gridDim.x * blockDim.x;
  for (int i = blockIdx.x * blockDim.x + t; i < TOTAL; i += stride) {
    unsigned k = keys[i];
    if (k >= K) {
      unsigned pos = atomicAdd(cnt, 1u);
      if (pos < CAND_MAX)
        cand[pos] = ((unsigned long long)k << 32) | (unsigned)(~(unsigned)i);
    }
  }
}

// O(N^2) exact rank over <= ~12010 cands; composite unique so ranks are a permutation;
// descending composite order == top_k (value desc, index asc). Thread with rank<12000
// decodes its box + score and CLEARS its remv bit if valid (remv defaults to all-ones,
// so unwritten ranks / invalid boxes stay suppressed).
__global__ void __launch_bounds__(256) k_rank(const unsigned* __restrict__ pcnt,
    const unsigned long long* __restrict__ cand,
    const float* __restrict__ deltas, const float* __restrict__ im_info,
    float4* __restrict__ boxes, float* __restrict__ scoresArr,
    unsigned long long* __restrict__ remvInit) {
  __shared__ unsigned long long tile[2048];
  unsigned cnt = *pcnt;
  if (cnt > CAND_MAX) cnt = CAND_MAX;
  int i = blockIdx.x * 256 + threadIdx.x;
  unsigned long long mine = (i < (int)cnt) ? cand[i] : 0ULL;
  int rank = 0;
  for (unsigned t0 = 0; t0 < cnt; t0 += 2048) {
    unsigned n = min(2048u, cnt - t0);
    __syncthreads();
    for (unsigned j = threadIdx.x; j < n; j += 256) tile[j] = cand[t0 + j];
    __syncthreads();
    if (i < (int)cnt) {
      int q0 = 0, q1 = 0, q2 = 0, q3 = 0;
      unsigned j = 0;
      #pragma unroll 4
      for (; j + 4 <= n; j += 4) {
        q0 += (tile[j]   > mine) ? 1 : 0;
        q1 += (tile[j+1] > mine) ? 1 : 0;
        q2 += (tile[j+2] > mine) ? 1 : 0;
        q3 += (tile[j+3] > mine) ? 1 : 0;
      }
      for (; j < n; j++) q0 += (tile[j] > mine) ? 1 : 0;
      rank += q0 + q1 + q2 + q3;
    }
  }
  if (i < (int)cnt && rank < PRE_NMS) {
    unsigned mono = (unsigned)(mine >> 32);
    unsigned idx = ~(unsigned)(mine & 0xFFFFFFFFull);
    unsigned u = (mono & 0x80000000u) ? (mono ^ 0x80000000u) : ~mono;
    float sc = __uint_as_float(u);
    int a = idx % NA;
    int base = idx / NA;
    int h = base / FW, w = base % FW;
    float x1, y1, x2, y2;
    decode_box(a, h, w, deltas, im_info[0], im_info[1], x1, y1, x2, y2);
    boxes[rank] = make_float4(x1, y1, x2, y2);
    scoresArr[rank] = sc;
    if (sc > -INFINITY)
      atomicAnd(&remvInit[rank >> 6], ~(1ULL << (rank & 63)));
  }
}

// Row-major suppression mask: mask[row][word], rows padded to MROW=192 words.
// Block (wg, bi) computes rows [bi*64, bi*64+64) x words [wg*8, wg*8+8):
// each thread accumulates 8 u64 in regs and stores 64 CONTIGUOUS bytes (full lines).
// Blocks with wg*8+7 < bi skipped: those poison words only ever get ORed into
// already-consumed past words in k_nms (harmless). Padding words 188..191 are
// written as zeros by wg=23 (sentinel boxes give IoU 0).
__global__ void __launch_bounds__(64) k_mask(const float4* __restrict__ boxes,
                                             unsigned long long* __restrict__ mask) {
  int wg = blockIdx.x;   // word group [0,24)
  int bi = blockIdx.y;   // row chunk  [0,188)
  if (wg * 8 + 7 < bi) return;
  __shared__ float4 jb[8][64];
  int t = threadIdx.x;
  #pragma unroll
  for (int k = 0; k < 8; k++) {
    int jg = (wg * 8 + k) * 64 + t;
    jb[k][t] = (jg < PRE_NMS) ? boxes[jg] : make_float4(0.f, 0.f, -1.f, -1.f);
  }
  __syncthreads();
  int i = bi * 64 + t;
  if (i >= PRE_NMS) return;
  float4 b = boxes[i];
  float area_i = (b.z - b.x + 1.0f) * (b.w - b.y + 1.0f);
  unsigned long long bits[8];
  #pragma unroll
  for (int k = 0; k < 8; k++) {
    unsigned long long bb = 0;
    for (int jj = 0; jj < 64; jj++) {
      float4 o = jb[k][jj];
      float xx1 = fmaxf(b.x, o.x);
      float yy1 = fmaxf(b.y, o.y);
      float xx2 = fminf(b.z, o.z);
      float yy2 = fminf(b.w, o.w);
      float iw = fmaxf(xx2 - xx1 + 1.0f, 0.0f);
      float ih = fmaxf(yy2 - yy1 + 1.0f, 0.0f);
      float inter = iw * ih;
      float area_o = (o.z - o.x + 1.0f) * (o.w - o.y + 1.0f);
      float iou = inter / (area_i + area_o - inter);
      if (iou > NMS_TH) bb |= (1ULL << jj);
    }
    bits[k] = bb;
  }
  size_t rb = (size_t)i * MROW + wg * 8;
  #pragma unroll
  for (int k = 0; k < 8; k++) mask[rb + k] = bits[k];
}

// Single-wave greedy NMS, eager distributed-register suppression state:
//   R[w] lives in 3 regs/lane (lane l owns words l, 64+l, 128+l), init from remvInit.
//   Keep j in chunk c -> its word c+1 contributes via preloaded nw1 regs + shfl reduce;
//   its FULL row is DMA'd (global_load_lds, no VGPR cost) into LDS staging and ORed
//   into R during chunk c+1 (covers words >= c+2; double-OR of c+1 is idempotent;
//   ORs into past/poison words are never read again).
__global__ void __launch_bounds__(64) k_nms(const unsigned long long* __restrict__ mask,
    const unsigned long long* __restrict__ remvI,
    const float4* __restrict__ boxes, const float* __restrict__ scoresArr,
    float* __restrict__ out) {
  extern __shared__ unsigned long long dyn[];
  unsigned long long* stage = dyn;                       // 64 rows x 192 words = 96 KiB
  unsigned* klist = (unsigned*)(dyn + 64 * MROW);        // 2000 u32
  int lane = threadIdx.x;  // 64
  unsigned long long r0 = remvI[lane];
  unsigned long long r1 = remvI[64 + lane];
  unsigned long long r2 = remvI[128 + lane];             // words 188..191 are 0xFF pad
  unsigned long long W = __shfl(r0, 0);                  // W_0 = R[0]
  unsigned long long diagc = mask[(size_t)lane * MROW + 0];
  unsigned long long nw1c  = mask[(size_t)lane * MROW + 1];
  int kept_cnt = 0, nkPrev = 0;
  bool done = false;
  for (int c = 0; c < NMS_WORDS; c++) {
    bool more = (c + 1 < NMS_WORDS);
    // 1. preload next chunk's diag / nw1 (coalesced; drained at step 4)
    unsigned long long diagN = 0, nw1N = 0;
    if (more) {
      size_t rb = (size_t)((c + 1) * 64 + lane) * MROW;
      diagN = mask[rb + (c + 1)];
      if (c + 2 < NMS_WORDS) nw1N = mask[rb + (c + 2)];
    }
    // 2. serial in-register resolve of chunk c (wave-uniform)
    int gi0 = c * 64;
    int jmax = PRE_NMS - gi0; if (jmax > 64) jmax = 64;
    unsigned long long avail = ~W;
    if (jmax < 64) avail &= ((1ULL << jmax) - 1ULL);
    unsigned long long keptmask = 0;
    while (avail) {
      int j = __ffsll((long long)avail) - 1;
      keptmask |= (1ULL << j);
      if (lane == 0) klist[kept_cnt] = (unsigned)(gi0 + j);
      kept_cnt++;
      if (kept_cnt >= POST_NMS) { done = true; break; }
      unsigned long long supp = __shfl(diagc, j);  // row (gi0+j)'s word c (self-bit set)
      avail &= ~supp;
      avail &= ~((2ULL << j) - 1ULL);              // clear bits <= j
    }
    if (done || !more) break;
    // 3. this chunk's keeps contribute word c+1 via preloaded nw1
    unsigned long long A = ((keptmask >> lane) & 1ULL) ? nw1c : 0ULL;
    // 4. drain chunk c-1's staging DMAs (+ our preloads)
    asm volatile("s_waitcnt vmcnt(0)" ::: "memory");
    __builtin_amdgcn_sched_barrier(0);
    // 5. OR staged rows (keeps of chunk c-1) into distributed R
    for (int s = 0; s < nkPrev; s++) {
      r0 |= stage[s * MROW + lane];
      r1 |= stage[s * MROW + 64 + lane];
      r2 |= stage[s * MROW + 128 + lane];
    }
    // 6. W_{c+1} = R[c+1] | reduce(A)
    unsigned long long x = A;
    #pragma unroll
    for (int off = 32; off; off >>= 1) x |= __shfl_xor(x, off);
    int cw = c + 1;
    unsigned long long Rw = ((cw >> 6) == 0) ? r0 : (((cw >> 6) == 1) ? r1 : r2);
    W = __shfl(Rw, cw & 63) | x;
    // 7. issue staging DMAs for this chunk's keeps (whole rows, 2 instrs each)
    int slot = 0;
    unsigned long long km = keptmask;
    while (km) {
      int j = __ffsll((long long)km) - 1; km &= km - 1;
      const char* rb = (const char*)(mask + (size_t)(gi0 + j) * MROW);
      char* lb = (char*)(void*)stage + slot * 1536;
      __builtin_amdgcn_global_load_lds(
          (const __attribute__((address_space(1))) unsigned*)(rb + lane * 16),
          (__attribute__((address_space(3))) unsigned*)lb, 16, 0, 0);
      if (lane < 30)
        __builtin_amdgcn_global_load_lds(
            (const __attribute__((address_space(1))) unsigned*)(rb + 1024 + lane * 16),
            (__attribute__((address_space(3))) unsigned*)(lb + 1024), 16, 0, 0);
      slot++;
    }
    nkPrev = slot;
    diagc = diagN; nw1c = nw1N;
  }
  // epilogue: rois + scores, zero-filled past kept_cnt
  __syncthreads();
  for (int s = lane; s < POST_NMS; s += 64) {
    float x1 = 0.f, y1 = 0.f, x2 = 0.f, y2 = 0.f, sc = 0.f;
    if (s < kept_cnt) {
      unsigned r = klist[s];
      float4 b = boxes[r];
      x1 = b.x; y1 = b.y; x2 = b.z; y2 = b.w;
      sc = scoresArr[r];
    }
    out[s*5 + 0] = 0.f;
    out[s*5 + 1] = x1;
    out[s*5 + 2] = y1;
    out[s*5 + 3] = x2;
    out[s*5 + 4] = y2;
    out[POST_NMS*5 + s] = sc;
  }
}

extern "C" void kernel_launch(void* const* d_in, const int* in_sizes, int n_in,
                              void* d_out, int out_size, void* d_ws, size_t ws_size,
                              hipStream_t stream) {
  const float* scores  = (const float*)d_in[0];
  const float* deltas  = (const float*)d_in[1];
  const float* im_info = (const float*)d_in[2];
  float* out = (float*)d_out;
  char* ws = (char*)d_ws;

  // workspace layout (bytes)
  unsigned* keys             = (unsigned*)(ws + 0);                 //  9,437,184
  unsigned* hist8            = (unsigned*)(ws + 9437184);           //  1,024
  unsigned* hist15           = (unsigned*)(ws + 9438208);           //  131,072
  unsigned* scal             = (unsigned*)(ws + 9569280);           //  256
  unsigned long long* remvI  = (unsigned long long*)(ws + 9569536); //  1,536 (192 words)
  unsigned long long* cand   = (unsigned long long*)(ws + 9571072); //  131,072
  float4* boxes              = (float4*)(ws + 9702144);             //  192,000
  float* scoresArr           = (float*)(ws + 9894144);              //  48,000
  unsigned long long* mask   = (unsigned long long*)(ws + 9942144); //  12000*1536 = 18,432,000 -> ~28.4 MB

  // hist8 + hist15 + scal -> 0 ; remvI -> all-ones (default-suppressed)
  hipMemsetAsync(ws + 9437184, 0, 132352, stream);
  hipMemsetAsync(ws + 9569536, 0xFF, 1536, stream);

  k_keys<<<HW/256, 256, 0, stream>>>(scores, deltas, im_info, keys, hist8);
  k_refine15<<<256, 256, 0, stream>>>(keys, hist8, hist15);
  k_compact<<<256, 256, 0, stream>>>(keys, hist8, hist15, &scal[4], cand);
  k_rank<<<CAND_MAX/256, 256, 0, stream>>>(&scal[4], cand, deltas, im_info,
                                           boxes, scoresArr, remvI);
  dim3 mg(24, 188);
  k_mask<<<mg, 64, 0, stream>>>(boxes, mask);

  (void)hipFuncSetAttribute((const void*)k_nms,
        hipFuncAttributeMaxDynamicSharedMemorySize, 64*MROW*8 + 2000*4);
  k_nms<<<1, 64, 64*MROW*8 + 2000*4, stream>>>(mask, remvI, boxes, scoresArr, out);
}